// Round 7
// baseline (568.065 us; speedup 1.0000x reference)
//
#include <hip/hip_runtime.h>
#include <hip/hip_bf16.h>

#define B_ 2
#define L_ 2048
#define S_ 2048
#define H_ 8
#define E_ 64
#define D_ 64

typedef __attribute__((ext_vector_type(8))) short bf16x8;
typedef __attribute__((ext_vector_type(4))) float f32x4;

#define MFMA(a, b, c) __builtin_amdgcn_mfma_f32_16x16x32_bf16(a, b, c, 0, 0, 0)

__device__ __forceinline__ short f2bf(float f) {
    unsigned u = __builtin_bit_cast(unsigned, f);
    u = (u + 0x7fffu + ((u >> 16) & 1u)) >> 16;
    return (short)u;
}

// pack two f32 -> two bf16 (compiler emits v_cvt_pk_bf16_f32)
__device__ __forceinline__ void cvt2(float a, float b, short& lo, short& hi) {
    __hip_bfloat162 h = __float22bfloat162_rn(make_float2(a, b));
    unsigned u;
    __builtin_memcpy(&u, &h, 4);
    lo = (short)(u & 0xffffu);
    hi = (short)(u >> 16);
}

// ---- fused prep: K -> Kb[bh][s][e] bf16 + kn2 ; VD/VW -> Vb[bh][d][s] bf16 ----
__global__ __launch_bounds__(256)
void prep_all(const float* __restrict__ K, const float* __restrict__ VD,
              const float* __restrict__ VW, short* __restrict__ Kb,
              float* __restrict__ kn2, short* __restrict__ VbD, short* __restrict__ VbW)
{
    __shared__ short tile[64][72];
    int blk = blockIdx.x;
    int t = threadIdx.x;
    if (blk < 2048) {
        int r = t >> 4, te = t & 15;
        int rowid = blk * 16 + r;             // bh*S + s
        int bh = rowid >> 11, s = rowid & 2047;
        int b = bh >> 3, h = bh & 7;
        const float4* src = (const float4*)(K + (((size_t)b * S_ + s) * H_ + h) * E_) + te;
        float4 x = *src;
        float sq = x.x * x.x + x.y * x.y + x.z * x.z + x.w * x.w;
#pragma unroll
        for (int off = 1; off < 16; off <<= 1) sq += __shfl_xor(sq, off);
        short4 o;
        o.x = f2bf(x.x); o.y = f2bf(x.y); o.z = f2bf(x.z); o.w = f2bf(x.w);
        *(short4*)(Kb + (size_t)rowid * 64 + te * 4) = o;
        if (te == 0) kn2[rowid] = sq;
    } else {
        int vb = blk - 2048;                  // 0..1023
        const float* V; short* Vb;
        if (vb < 512) { V = VD; Vb = VbD; } else { V = VW; Vb = VbW; vb -= 512; }
        int st = vb & 31, bh = vb >> 5;
        int b = bh >> 3, h = bh & 7;
        int s0 = st * 64;
        {
            int i = t >> 2, q = t & 3;
            const float4* s4 = (const float4*)(V + (((size_t)b * S_ + s0 + i) * H_ + h) * D_ + q * 16);
#pragma unroll
            for (int j = 0; j < 4; j++) {
                float4 x = s4[j];
                short4 o;
                o.x = f2bf(x.x); o.y = f2bf(x.y); o.z = f2bf(x.z); o.w = f2bf(x.w);
                *(short4*)&tile[i][q * 16 + j * 4] = o;
            }
        }
        __syncthreads();
        {
            int d = t >> 2, q = t & 3;
            short v16[16];
#pragma unroll
            for (int k = 0; k < 16; k++) v16[k] = tile[q * 16 + k][d];
            short* dst = Vb + ((size_t)bh * 64 + d) * S_ + s0 + q * 16;
            ((int4*)dst)[0] = ((int4*)v16)[0];
            ((int4*)dst)[1] = ((int4*)v16)[1];
        }
    }
}

// Pipelined body: compute s-chunk S0 using K regs KC*/KNC*, prefetch chunk SN
// into KN*/KNN*. V loads split: group A at top, group B after P-LDS write.
#define BODY(S0, SN, KC0, KC1, KC2, KC3, KNC0, KNC1, KN0, KN1, KN2, KN3, KNN0, KNN1) { \
    bf16x8 vfd0 = *(const bf16x8*)(vdl + (S0)); \
    bf16x8 vfd1 = *(const bf16x8*)(vdl + 16 * S_ + (S0)); \
    bf16x8 vfw0 = *(const bf16x8*)(vwl + (S0)); \
    bf16x8 vfw1 = *(const bf16x8*)(vwl + 16 * S_ + (S0)); \
    __builtin_amdgcn_s_setprio(1); \
    f32x4 cd0 = MFMA(a_frag[0], KC0, zero4); cd0 = MFMA(a_frag[1], KC1, cd0); \
    f32x4 cd1 = MFMA(a_frag[0], KC2, zero4); cd1 = MFMA(a_frag[1], KC3, cd1); \
    __builtin_amdgcn_s_setprio(0); \
    KN0 = *(const bf16x8*)(kbl + (size_t)(SN) * 64); \
    KN1 = *(const bf16x8*)(kbl + (size_t)(SN) * 64 + 32); \
    KN2 = *(const bf16x8*)(kbl + (size_t)((SN) + 16) * 64); \
    KN3 = *(const bf16x8*)(kbl + (size_t)((SN) + 16) * 64 + 32); \
    KNN0 = kn2l[(SN)]; KNN1 = kn2l[(SN) + 16]; \
    float pd0[4], pd1[4], pw0[4], pw1[4]; \
    _Pragma("unroll") \
    for (int r = 0; r < 4; r++) { \
        float d0 = cd0[r] * scale, d1 = cd1[r] * scale; \
        float w0 = sqrtf(fmaxf(__builtin_fmaf(-d0, d0, qn2s[r] * (KNC0)), 0.f) + 1.5625e-10f); \
        float w1 = sqrtf(fmaxf(__builtin_fmaf(-d1, d1, qn2s[r] * (KNC1)), 0.f) + 1.5625e-10f); \
        regsum += fabsf(d0) + fabsf(d1) + (w0 + w1); \
        pd0[r] = exp2f(__builtin_fmaf(d0, 1.4426950408889634f, MDL)); \
        pd1[r] = exp2f(__builtin_fmaf(d1, 1.4426950408889634f, MDL)); \
        pw0[r] = exp2f(__builtin_fmaf(w0, 1.4426950408889634f, MWL)); \
        pw1[r] = exp2f(__builtin_fmaf(w1, 1.4426950408889634f, MWL)); \
        lacc_d[r] += pd0[r] + pd1[r]; \
        lacc_w[r] += pw0[r] + pw1[r]; \
    } \
    _Pragma("unroll") \
    for (int r = 0; r < 4; r++) { \
        short lo, hi; \
        cvt2(pd0[r], pd1[r], lo, hi); \
        plds[wid][0][4 * g + r][c]      = lo; \
        plds[wid][0][4 * g + r][16 + c] = hi; \
        cvt2(pw0[r], pw1[r], lo, hi); \
        plds[wid][1][4 * g + r][c]      = lo; \
        plds[wid][1][4 * g + r][16 + c] = hi; \
    } \
    bf16x8 vfd2 = *(const bf16x8*)(vdl + (size_t)2 * 16 * S_ + (S0)); \
    bf16x8 vfd3 = *(const bf16x8*)(vdl + (size_t)3 * 16 * S_ + (S0)); \
    bf16x8 vfw2 = *(const bf16x8*)(vwl + (size_t)2 * 16 * S_ + (S0)); \
    bf16x8 vfw3 = *(const bf16x8*)(vwl + (size_t)3 * 16 * S_ + (S0)); \
    bf16x8 pa_d = *(const bf16x8*)&plds[wid][0][c][g * 8]; \
    bf16x8 pa_w = *(const bf16x8*)&plds[wid][1][c][g * 8]; \
    __builtin_amdgcn_s_setprio(1); \
    o_d[0] = MFMA(pa_d, vfd0, o_d[0]); o_w[0] = MFMA(pa_w, vfw0, o_w[0]); \
    o_d[1] = MFMA(pa_d, vfd1, o_d[1]); o_w[1] = MFMA(pa_w, vfw1, o_w[1]); \
    o_d[2] = MFMA(pa_d, vfd2, o_d[2]); o_w[2] = MFMA(pa_w, vfw2, o_w[2]); \
    o_d[3] = MFMA(pa_d, vfd3, o_d[3]); o_w[3] = MFMA(pa_w, vfw3, o_w[3]); \
    __builtin_amdgcn_s_setprio(0); \
}

__global__ __launch_bounds__(512, 4)
void dual_attn(const float* __restrict__ Q, const short* __restrict__ Kb,
               const float* __restrict__ kn2g, const short* __restrict__ VbD,
               const short* __restrict__ VbW, const float* __restrict__ FG,
               float* __restrict__ out, float* __restrict__ regacc)
{
    int bid = blockIdx.x;
    int wg  = (bid & 7) * 128 + (bid >> 3);   // bijective XCD swizzle (1024 = 8*128)
    int bh  = wg >> 6;                         // 2 bh per XCD -> K/V L2-resident
    int qt  = wg & 63;                         // 64 groups of 32 q-rows
    int b = bh >> 3, h = bh & 7;

    int tid  = threadIdx.x;
    int wid  = tid >> 6;                       // 0..7
    int lane = tid & 63;
    int g = lane >> 4;
    int c = lane & 15;
    int qsub  = wid & 1;                       // 16-row subtile within the 32
    int split = wid >> 1;                      // s-range 0..3

    int q0 = qt * 32;
    int qrow0 = q0 + qsub * 16;

    __shared__ __align__(16) char smem[20608];
    short (*plds)[2][16][40] = (short (*)[2][16][40])smem;   // [8][2][16][40] = 20480 B

    // ---- Q fragments (A operand) + row squared-norms ----
    bf16x8 a_frag[2];
    float qn2 = 0.f;
    {
        const float* qp = Q + (((size_t)b * L_ + qrow0 + c) * H_ + h) * E_ + g * 8;
#pragma unroll
        for (int kk = 0; kk < 2; kk++) {
            const float4* p4 = (const float4*)(qp + kk * 32);
            float4 x0 = p4[0], x1 = p4[1];
            float v[8] = {x0.x, x0.y, x0.z, x0.w, x1.x, x1.y, x1.z, x1.w};
#pragma unroll
            for (int j = 0; j < 8; j++) { qn2 += v[j] * v[j]; a_frag[kk][j] = f2bf(v[j]); }
        }
        qn2 += __shfl_xor(qn2, 16);
        qn2 += __shfl_xor(qn2, 32);
    }
    float qn2s[4];   // pre-scaled by scale^2 = 1/64
#pragma unroll
    for (int r = 0; r < 4; r++) qn2s[r] = __shfl(qn2, g * 4 + r) * 0.015625f;

    f32x4 zero4 = {0.f, 0.f, 0.f, 0.f};
    f32x4 o_d[4] = {zero4, zero4, zero4, zero4};
    f32x4 o_w[4] = {zero4, zero4, zero4, zero4};
    float lacc_d[4] = {0.f, 0.f, 0.f, 0.f};
    float lacc_w[4] = {0.f, 0.f, 0.f, 0.f};
    float regsum = 0.f;
    const float scale = 0.125f;
    // fixed softmax shifts (Cauchy-Schwarz-safe), pre-multiplied by log2(e)
    const float MDL = -8.0f  * 1.4426950408889634f;
    const float MWL = -16.0f * 1.4426950408889634f;

    const short* kbl  = Kb   + (size_t)bh * (S_ * 64) + c * 64 + g * 8;
    const float* kn2l = kn2g + (size_t)bh * S_ + c;
    const short* vdl  = VbD  + (size_t)bh * (64 * S_) + c * S_ + g * 8;
    const short* vwl  = VbW  + (size_t)bh * (64 * S_) + c * S_ + g * 8;

    const int sbeg = split * 512, send = sbeg + 512;

    // ---- software-pipelined main loop: K/kn2 double-buffered in regs ----
    bf16x8 kA0, kA1, kA2, kA3, kB0, kB1, kB2, kB3;
    float knA0, knA1, knB0, knB1;
    kA0 = *(const bf16x8*)(kbl + (size_t)sbeg * 64);
    kA1 = *(const bf16x8*)(kbl + (size_t)sbeg * 64 + 32);
    kA2 = *(const bf16x8*)(kbl + (size_t)(sbeg + 16) * 64);
    kA3 = *(const bf16x8*)(kbl + (size_t)(sbeg + 16) * 64 + 32);
    knA0 = kn2l[sbeg]; knA1 = kn2l[sbeg + 16];

#pragma unroll 1
    for (int s0 = sbeg; s0 < send; s0 += 64) {
        int sn1 = s0 + 32;
        int sn2 = (s0 + 64 < send) ? (s0 + 64) : sbeg;
        BODY(s0,  sn1, kA0, kA1, kA2, kA3, knA0, knA1, kB0, kB1, kB2, kB3, knB0, knB1)
        BODY(sn1, sn2, kB0, kB1, kB2, kB3, knB0, knB1, kA0, kA1, kA2, kA3, knA0, knA1)
    }

    // ---- in-wave l reduce (16-col groups) ----
#pragma unroll
    for (int r = 0; r < 4; r++) {
#pragma unroll
        for (int off = 1; off < 16; off <<= 1) {
            lacc_d[r] += __shfl_xor(lacc_d[r], off);
            lacc_w[r] += __shfl_xor(lacc_w[r], off);
        }
    }

    // ---- regsum: wave reduce + one atomic ----
#pragma unroll
    for (int off = 1; off < 64; off <<= 1) regsum += __shfl_xor(regsum, off);
    if (lane == 0) atomicAdd(regacc, regsum);

    // ---- cross-split combine in LDS (fixed-M => partials are additive) ----
    __syncthreads();                      // all waves done with plds
    float* smf = (float*)smem;
    const int OB = 2 * 32 * 68;           // obuf floats (pad 68: 16B-aligned rows)
    for (int i = tid; i < OB + 64; i += 512) smf[i] = 0.f;
    __syncthreads();
    float (*obuf)[32][68] = (float (*)[32][68])smem;
    float* lbuf = smf + OB;               // [2][32]
#pragma unroll
    for (int r = 0; r < 4; r++) {
        int row = qsub * 16 + 4 * g + r;
#pragma unroll
        for (int dt = 0; dt < 4; dt++) {
            atomicAdd(&obuf[0][row][dt * 16 + c], o_d[dt][r]);
            atomicAdd(&obuf[1][row][dt * 16 + c], o_w[dt][r]);
        }
        if (c == 0) {
            atomicAdd(&lbuf[row], lacc_d[r]);
            atomicAdd(&lbuf[32 + row], lacc_w[r]);
        }
    }
    __syncthreads();

    // ---- blend + store: 512 threads cover 32 rows x 16 float4 ----
    float fgv  = FG[0];
    float gate = 1.f / (1.f + __expf(-fgv));
    float omg  = 1.f - gate;
    int row  = tid >> 4;
    int dcol = (tid & 15) * 4;
    float4 od = *(float4*)&obuf[0][row][dcol];
    float4 ow = *(float4*)&obuf[1][row][dcol];
    float ild = 1.f / lbuf[row];
    float ilw = 1.f / lbuf[32 + row];
    float4 res;
    res.x = omg * od.x * ild + gate * ow.x * ilw;
    res.y = omg * od.y * ild + gate * ow.y * ilw;
    res.z = omg * od.z * ild + gate * ow.z * ilw;
    res.w = omg * od.w * ild + gate * ow.w * ilw;
    *(float4*)(out + (((size_t)b * L_ + q0 + row) * H_ + h) * D_ + dcol) = res;
}

__global__ void finalize_reg(const float* __restrict__ regacc, float* __restrict__ out)
{
    out[B_ * L_ * H_ * D_] = regacc[0] * (1.0f / 134217728.0f);
}

extern "C" void kernel_launch(void* const* d_in, const int* in_sizes, int n_in,
                              void* d_out, int out_size, void* d_ws, size_t ws_size,
                              hipStream_t stream)
{
    const float* Q  = (const float*)d_in[0];
    const float* K  = (const float*)d_in[1];
    const float* VD = (const float*)d_in[2];
    const float* VW = (const float*)d_in[3];
    const float* FG = (const float*)d_in[4];
    float* out = (float*)d_out;

    char* ws = (char*)d_ws;
    float* regacc = (float*)ws;                                  // 4 B
    float* kn2    = (float*)(ws + 256);                          // 128 KiB
    short* Kb     = (short*)(ws + 256 + 131072);                 // 4 MiB
    short* VbD    = (short*)(ws + 256 + 131072 + 4194304);       // 4 MiB
    short* VbW    = (short*)(ws + 256 + 131072 + 8388608);       // 4 MiB

    (void)hipMemsetAsync(regacc, 0, sizeof(float), stream);
    prep_all<<<dim3(3072), dim3(256), 0, stream>>>(K, VD, VW, Kb, kn2, VbD, VbW);
    dual_attn<<<dim3(1024), dim3(512), 0, stream>>>(Q, Kb, kn2, VbD, VbW, FG, out, regacc);
    finalize_reg<<<1, 1, 0, stream>>>(regacc, out);
}

// Round 8
// 391.517 us; speedup vs baseline: 1.4509x; 1.4509x over previous
//
#include <hip/hip_runtime.h>
#include <hip/hip_bf16.h>

#define B_ 2
#define L_ 2048
#define S_ 2048
#define H_ 8
#define E_ 64
#define D_ 64

typedef __attribute__((ext_vector_type(8))) short bf16x8;
typedef __attribute__((ext_vector_type(4))) float f32x4;

#define MFMA(a, b, c) __builtin_amdgcn_mfma_f32_16x16x32_bf16(a, b, c, 0, 0, 0)

__device__ __forceinline__ short f2bf(float f) {
    unsigned u = __builtin_bit_cast(unsigned, f);
    u = (u + 0x7fffu + ((u >> 16) & 1u)) >> 16;
    return (short)u;
}

// pack two f32 -> two bf16 (compiler emits v_cvt_pk_bf16_f32)
__device__ __forceinline__ void cvt2(float a, float b, short& lo, short& hi) {
    __hip_bfloat162 h = __float22bfloat162_rn(make_float2(a, b));
    unsigned u;
    __builtin_memcpy(&u, &h, 4);
    lo = (short)(u & 0xffffu);
    hi = (short)(u >> 16);
}

// ---- fused prep: K -> Kb[bh][s][e] bf16 + kn2 ; VD/VW -> Vb[bh][d][s] bf16 ----
__global__ __launch_bounds__(256)
void prep_all(const float* __restrict__ K, const float* __restrict__ VD,
              const float* __restrict__ VW, short* __restrict__ Kb,
              float* __restrict__ kn2, short* __restrict__ VbD, short* __restrict__ VbW)
{
    __shared__ short tile[64][72];
    int blk = blockIdx.x;
    int t = threadIdx.x;
    if (blk < 2048) {
        int r = t >> 4, te = t & 15;
        int rowid = blk * 16 + r;             // bh*S + s
        int bh = rowid >> 11, s = rowid & 2047;
        int b = bh >> 3, h = bh & 7;
        const float4* src = (const float4*)(K + (((size_t)b * S_ + s) * H_ + h) * E_) + te;
        float4 x = *src;
        float sq = x.x * x.x + x.y * x.y + x.z * x.z + x.w * x.w;
#pragma unroll
        for (int off = 1; off < 16; off <<= 1) sq += __shfl_xor(sq, off);
        short4 o;
        o.x = f2bf(x.x); o.y = f2bf(x.y); o.z = f2bf(x.z); o.w = f2bf(x.w);
        *(short4*)(Kb + (size_t)rowid * 64 + te * 4) = o;
        if (te == 0) kn2[rowid] = sq;
    } else {
        int vb = blk - 2048;                  // 0..1023
        const float* V; short* Vb;
        if (vb < 512) { V = VD; Vb = VbD; } else { V = VW; Vb = VbW; vb -= 512; }
        int st = vb & 31, bh = vb >> 5;
        int b = bh >> 3, h = bh & 7;
        int s0 = st * 64;
        {
            int i = t >> 2, q = t & 3;
            const float4* s4 = (const float4*)(V + (((size_t)b * S_ + s0 + i) * H_ + h) * D_ + q * 16);
#pragma unroll
            for (int j = 0; j < 4; j++) {
                float4 x = s4[j];
                short4 o;
                o.x = f2bf(x.x); o.y = f2bf(x.y); o.z = f2bf(x.z); o.w = f2bf(x.w);
                *(short4*)&tile[i][q * 16 + j * 4] = o;
            }
        }
        __syncthreads();
        {
            int d = t >> 2, q = t & 3;
            short v16[16];
#pragma unroll
            for (int k = 0; k < 16; k++) v16[k] = tile[q * 16 + k][d];
            short* dst = Vb + ((size_t)bh * 64 + d) * S_ + s0 + q * 16;
            ((int4*)dst)[0] = ((int4*)v16)[0];
            ((int4*)dst)[1] = ((int4*)v16)[1];
        }
    }
}

__global__ __launch_bounds__(512, 4)
void dual_attn(const float* __restrict__ Q, const short* __restrict__ Kb,
               const float* __restrict__ kn2g, const short* __restrict__ VbD,
               const short* __restrict__ VbW, const float* __restrict__ FG,
               float* __restrict__ out, float* __restrict__ regacc)
{
    int bid = blockIdx.x;
    int wg  = (bid & 7) * 128 + (bid >> 3);   // bijective XCD swizzle (1024 = 8*128)
    int bh  = wg >> 6;                         // 2 bh per XCD -> K/V L2-resident
    int qt  = wg & 63;                         // 64 groups of 32 q-rows
    int b = bh >> 3, h = bh & 7;

    int tid  = threadIdx.x;
    int wid  = tid >> 6;                       // 0..7
    int lane = tid & 63;
    int g = lane >> 4;
    int c = lane & 15;
    int qsub  = wid & 1;                       // 16-row subtile within the 32
    int split = wid >> 1;                      // s-range 0..3

    int q0 = qt * 32;
    int qrow0 = q0 + qsub * 16;

    __shared__ __align__(16) char smem[20608];
    short (*plds)[2][16][40] = (short (*)[2][16][40])smem;   // [8][2][16][40] = 20480 B

    // ---- Q fragments (A operand) + row squared-norms ----
    bf16x8 a_frag[2];
    float qn2 = 0.f;
    {
        const float* qp = Q + (((size_t)b * L_ + qrow0 + c) * H_ + h) * E_ + g * 8;
#pragma unroll
        for (int kk = 0; kk < 2; kk++) {
            const float4* p4 = (const float4*)(qp + kk * 32);
            float4 x0 = p4[0], x1 = p4[1];
            float v[8] = {x0.x, x0.y, x0.z, x0.w, x1.x, x1.y, x1.z, x1.w};
#pragma unroll
            for (int j = 0; j < 8; j++) { qn2 += v[j] * v[j]; a_frag[kk][j] = f2bf(v[j]); }
        }
        qn2 += __shfl_xor(qn2, 16);
        qn2 += __shfl_xor(qn2, 32);
    }
    float qn2s[4];   // pre-scaled by scale^2 = 1/64
#pragma unroll
    for (int r = 0; r < 4; r++) qn2s[r] = __shfl(qn2, g * 4 + r) * 0.015625f;

    f32x4 zero4 = {0.f, 0.f, 0.f, 0.f};
    f32x4 o_d[4] = {zero4, zero4, zero4, zero4};
    f32x4 o_w[4] = {zero4, zero4, zero4, zero4};
    float lacc_d[4] = {0.f, 0.f, 0.f, 0.f};
    float lacc_w[4] = {0.f, 0.f, 0.f, 0.f};
    float regsum = 0.f;
    const float scale = 0.125f;
    // fixed softmax shifts (Cauchy-Schwarz-safe), pre-multiplied by log2(e)
    const float MDL = -8.0f  * 1.4426950408889634f;
    const float MWL = -16.0f * 1.4426950408889634f;
    const float L2E = 1.4426950408889634f;

    const short* kbl  = Kb   + (size_t)bh * (S_ * 64) + c * 64 + g * 8;
    const float* kn2l = kn2g + (size_t)bh * S_ + c;
    const short* vdl  = VbD  + (size_t)bh * (64 * S_) + c * S_ + g * 8;
    const short* vwl  = VbW  + (size_t)bh * (64 * S_) + c * S_ + g * 8;

    const int sbeg = split * 512, send = sbeg + 512;
#pragma unroll 2
    for (int s0 = sbeg; s0 < send; s0 += 32) {
        bf16x8 bf00 = *(const bf16x8*)(kbl + (size_t)(s0 +  0) * 64);
        bf16x8 bf01 = *(const bf16x8*)(kbl + (size_t)(s0 +  0) * 64 + 32);
        bf16x8 bf10 = *(const bf16x8*)(kbl + (size_t)(s0 + 16) * 64);
        bf16x8 bf11 = *(const bf16x8*)(kbl + (size_t)(s0 + 16) * 64 + 32);
        float kn20 = kn2l[s0], kn21 = kn2l[s0 + 16];

        f32x4 cd0 = MFMA(a_frag[0], bf00, zero4);
        cd0 = MFMA(a_frag[1], bf01, cd0);
        f32x4 cd1 = MFMA(a_frag[0], bf10, zero4);
        cd1 = MFMA(a_frag[1], bf11, cd1);

        float pd0[4], pd1[4], pw0[4], pw1[4];
#pragma unroll
        for (int r = 0; r < 4; r++) {
            float d0 = cd0[r] * scale, d1 = cd1[r] * scale;
            float w0 = sqrtf(fmaxf(__builtin_fmaf(-d0, d0, qn2s[r] * kn20), 0.f) + 1.5625e-10f);
            float w1 = sqrtf(fmaxf(__builtin_fmaf(-d1, d1, qn2s[r] * kn21), 0.f) + 1.5625e-10f);
            regsum += fabsf(d0) + fabsf(d1) + (w0 + w1);
            pd0[r] = exp2f(__builtin_fmaf(d0, L2E, MDL));
            pd1[r] = exp2f(__builtin_fmaf(d1, L2E, MDL));
            pw0[r] = exp2f(__builtin_fmaf(w0, L2E, MWL));
            pw1[r] = exp2f(__builtin_fmaf(w1, L2E, MWL));
            lacc_d[r] += pd0[r] + pd1[r];
            lacc_w[r] += pw0[r] + pw1[r];
        }

        // P transpose (C layout -> A fragment layout) via per-wave LDS; packed cvt
#pragma unroll
        for (int r = 0; r < 4; r++) {
            short lo, hi;
            cvt2(pd0[r], pd1[r], lo, hi);
            plds[wid][0][4 * g + r][c]      = lo;
            plds[wid][0][4 * g + r][16 + c] = hi;
            cvt2(pw0[r], pw1[r], lo, hi);
            plds[wid][1][4 * g + r][c]      = lo;
            plds[wid][1][4 * g + r][16 + c] = hi;
        }
        bf16x8 pa_d = *(const bf16x8*)&plds[wid][0][c][g * 8];
        bf16x8 pa_w = *(const bf16x8*)&plds[wid][1][c][g * 8];

#pragma unroll
        for (int dt = 0; dt < 4; dt++) {
            bf16x8 vf_d = *(const bf16x8*)(vdl + (size_t)dt * 16 * S_ + s0);
            bf16x8 vf_w = *(const bf16x8*)(vwl + (size_t)dt * 16 * S_ + s0);
            o_d[dt] = MFMA(pa_d, vf_d, o_d[dt]);
            o_w[dt] = MFMA(pa_w, vf_w, o_w[dt]);
        }
    }

    // ---- in-wave l reduce (16-col groups) ----
#pragma unroll
    for (int r = 0; r < 4; r++) {
#pragma unroll
        for (int off = 1; off < 16; off <<= 1) {
            lacc_d[r] += __shfl_xor(lacc_d[r], off);
            lacc_w[r] += __shfl_xor(lacc_w[r], off);
        }
    }

    // ---- regsum: wave reduce + one atomic ----
#pragma unroll
    for (int off = 1; off < 64; off <<= 1) regsum += __shfl_xor(regsum, off);
    if (lane == 0) atomicAdd(regacc, regsum);

    // ---- cross-split combine in LDS (fixed-M => partials are additive) ----
    __syncthreads();                      // all waves done with plds
    float* smf = (float*)smem;
    const int OB = 2 * 32 * 68;           // obuf floats (pad 68: 16B-aligned rows)
    for (int i = tid; i < OB + 64; i += 512) smf[i] = 0.f;
    __syncthreads();
    float (*obuf)[32][68] = (float (*)[32][68])smem;
    float* lbuf = smf + OB;               // [2][32]
#pragma unroll
    for (int r = 0; r < 4; r++) {
        int row = qsub * 16 + 4 * g + r;
#pragma unroll
        for (int dt = 0; dt < 4; dt++) {
            atomicAdd(&obuf[0][row][dt * 16 + c], o_d[dt][r]);
            atomicAdd(&obuf[1][row][dt * 16 + c], o_w[dt][r]);
        }
        if (c == 0) {
            atomicAdd(&lbuf[row], lacc_d[r]);
            atomicAdd(&lbuf[32 + row], lacc_w[r]);
        }
    }
    __syncthreads();

    // ---- blend + store: 512 threads cover 32 rows x 16 float4 ----
    float fgv  = FG[0];
    float gate = 1.f / (1.f + __expf(-fgv));
    float omg  = 1.f - gate;
    int row  = tid >> 4;
    int dcol = (tid & 15) * 4;
    float4 od = *(float4*)&obuf[0][row][dcol];
    float4 ow = *(float4*)&obuf[1][row][dcol];
    float ild = 1.f / lbuf[row];
    float ilw = 1.f / lbuf[32 + row];
    float4 res;
    res.x = omg * od.x * ild + gate * ow.x * ilw;
    res.y = omg * od.y * ild + gate * ow.y * ilw;
    res.z = omg * od.z * ild + gate * ow.z * ilw;
    res.w = omg * od.w * ild + gate * ow.w * ilw;
    *(float4*)(out + (((size_t)b * L_ + q0 + row) * H_ + h) * D_ + dcol) = res;
}

__global__ void finalize_reg(const float* __restrict__ regacc, float* __restrict__ out)
{
    out[B_ * L_ * H_ * D_] = regacc[0] * (1.0f / 134217728.0f);
}

extern "C" void kernel_launch(void* const* d_in, const int* in_sizes, int n_in,
                              void* d_out, int out_size, void* d_ws, size_t ws_size,
                              hipStream_t stream)
{
    const float* Q  = (const float*)d_in[0];
    const float* K  = (const float*)d_in[1];
    const float* VD = (const float*)d_in[2];
    const float* VW = (const float*)d_in[3];
    const float* FG = (const float*)d_in[4];
    float* out = (float*)d_out;

    char* ws = (char*)d_ws;
    float* regacc = (float*)ws;                                  // 4 B
    float* kn2    = (float*)(ws + 256);                          // 128 KiB
    short* Kb     = (short*)(ws + 256 + 131072);                 // 4 MiB
    short* VbD    = (short*)(ws + 256 + 131072 + 4194304);       // 4 MiB
    short* VbW    = (short*)(ws + 256 + 131072 + 8388608);       // 4 MiB

    (void)hipMemsetAsync(regacc, 0, sizeof(float), stream);
    prep_all<<<dim3(3072), dim3(256), 0, stream>>>(K, VD, VW, Kb, kn2, VbD, VbW);
    dual_attn<<<dim3(1024), dim3(512), 0, stream>>>(Q, Kb, kn2, VbD, VbW, FG, out, regacc);
    finalize_reg<<<1, 1, 0, stream>>>(regacc, out);
}